// Round 9
// baseline (149.679 us; speedup 1.0000x reference)
//
#include <hip/hip_runtime.h>

#define NB     64
#define NOBJ   50
#define ND     8732
#define BLK    256
#define NW     (BLK/64)              // 4 waves
#define PPT    4
#define PRB    (BLK*PPT)             // 1024 priors per block
#define NBA    9                     // ceil(8732/1024); last split 540
#define CH     10
#define NCH    5
#define BLK2   1024
#define NW2    (BLK2/64)
#define ITER2  ((ND+BLK2-1)/BLK2)    // 9
#define ND4    (ND/4)

// device scratch — every element rewritten each launch (graph-replay safe, deterministic)
__device__ float              g_part[NB*5];
__device__ float4             g_ce4[(size_t)NB*ND4];       // signed ce_mined (pos -> -ce_pos)
__device__ unsigned long long g_kpart[NB*NBA*NOBJ];        // per-split per-truth keys
__device__ int                g_hist[(size_t)NB*NBA*256];
__device__ float              g_bp[NB*NBA*3];
__device__ int                g_done;

// division-free IoU pieces; bit-identical in k1 and k2-correction
__device__ __forceinline__ void iou_parts(float px1,float py1,float px2,float py2,float pa,
                                          float tx1,float ty1,float tx2,float ty2,float ta,
                                          float& inter,float& den){
    float ltx=fmaxf(tx1,px1), lty=fmaxf(ty1,py1);
    float rbx=fminf(tx2,px2), rby=fminf(ty2,py2);
    float ww=fmaxf(__fsub_rn(rbx,ltx),0.f), hh=fmaxf(__fsub_rn(rby,lty),0.f);
    inter=__fmul_rn(ww,hh);
    den=__fsub_rn(__fadd_rn(ta,pa),inter);
}
// strict "new beats old" under cross-multiplication (dens > 0)
__device__ __forceinline__ bool better(float iN,float dN,float iO,float dO){
    return __fmul_rn(iN,dO) > __fmul_rn(iO,dN);
}
__device__ __forceinline__ float lse2(float x0,float x1){
    float m=fmaxf(x0,x1);
    return m+__logf(__expf(x0-m)+__expf(x1-m));
}
__device__ __forceinline__ float sl1_enc(float4 p,float tx1,float ty1,float tx2,float ty2,float4 ld){
    float g0=((tx1+tx2)*0.5f-p.x)/(0.1f*p.z);
    float g1=((ty1+ty2)*0.5f-p.y)/(0.1f*p.w);
    float g2=__logf((tx2-tx1)/p.z)*5.0f;
    float g3=__logf((ty2-ty1)/p.w)*5.0f;
    float t0=fabsf(ld.x-g0),t1=fabsf(ld.y-g1),t2=fabsf(ld.z-g2),t3=fabsf(ld.w-g3);
    return (t0<1.f?0.5f*t0*t0:t0-0.5f)+(t1<1.f?0.5f*t1*t1:t1-0.5f)
          +(t2<1.f?0.5f*t2*t2:t2-0.5f)+(t3<1.f?0.5f*t3*t3:t3-0.5f);
}

// ---------------- K1: division-free joint match + CE/L1/hist ----------------
__global__ __launch_bounds__(BLK) void k1(const float* __restrict__ loc_data,
                                          const float* __restrict__ conf_data,
                                          const float* __restrict__ dbox,
                                          const float* __restrict__ targets){
    __shared__ float s_tx1[NOBJ],s_ty1[NOBJ],s_tx2[NOBJ],s_ty2[NOBJ],s_lab[NOBJ];
    __shared__ unsigned long long s_wk[NW][NOBJ];
    __shared__ int   s_wh[NW*256];
    __shared__ float s_r1[NW],s_r2[NW],s_r3[NW];

    const int blk=blockIdx.x, b=blk/NBA, spl=blk%NBA;
    const int tid=threadIdx.x, lane=tid&63, wv=tid>>6;
    const float4* dbox4=reinterpret_cast<const float4*>(dbox);
    if (blk==0 && tid==0) g_done=0;

    if (tid<NOBJ){
        const float* t=targets+(b*NOBJ+tid)*5;
        s_tx1[tid]=t[0];s_ty1[tid]=t[1];s_tx2[tid]=t[2];s_ty2[tid]=t[3];s_lab[tid]=t[4];
    }
    for (int i=tid;i<NW*256;i+=BLK) s_wh[i]=0;
    __syncthreads();

    const int d0=spl*PRB;
    const bool vld=(d0+tid*PPT)<ND;
    float px1[PPT],py1[PPT],px2[PPT],py2[PPT],pa[PPT];
    float ibest[PPT],dbest[PPT]; int bj[PPT];
#pragma unroll
    for (int q=0;q<PPT;++q){
        ibest[q]=-1.f; dbest[q]=1.f; bj[q]=0;
        px1[q]=py1[q]=px2[q]=py2[q]=pa[q]=0.f;
        if (vld){
            float4 p=dbox4[d0+tid*PPT+q];
            float hw=__fmul_rn(0.5f,p.z), hh=__fmul_rn(0.5f,p.w);
            px1[q]=__fsub_rn(p.x,hw); py1[q]=__fsub_rn(p.y,hh);
            px2[q]=__fadd_rn(p.x,hw); py2[q]=__fadd_rn(p.y,hh);
            pa[q]=__fmul_rn(p.z,p.w);
        }
    }

    const float* tg=targets+(size_t)b*NOBJ*5;
#pragma unroll 1
    for (int c=0;c<NCH;++c){
        float tx1c[CH],ty1c[CH],tx2c[CH],ty2c[CH],tac[CH];
#pragma unroll
        for (int jj=0;jj<CH;++jj){
            int j=c*CH+jj;
            tx1c[jj]=tg[j*5+0]; ty1c[jj]=tg[j*5+1];
            tx2c[jj]=tg[j*5+2]; ty2c[jj]=tg[j*5+3];
            tac[jj]=__fmul_rn(__fsub_rn(tx2c[jj],tx1c[jj]),__fsub_rn(ty2c[jj],ty1c[jj]));
        }
        float tiN[CH],tdN[CH]; int tdd[CH];
#pragma unroll
        for (int jj=0;jj<CH;++jj){tiN[jj]=-1.f;tdN[jj]=1.f;tdd[jj]=0;}

        if (vld){
#pragma unroll
            for (int q=0;q<PPT;++q){
                const int d=d0+tid*PPT+q;
#pragma unroll
                for (int jj=0;jj<CH;++jj){
                    float inter,den;
                    iou_parts(px1[q],py1[q],px2[q],py2[q],pa[q],
                              tx1c[jj],ty1c[jj],tx2c[jj],ty2c[jj],tac[jj],inter,den);
                    if (better(inter,den,ibest[q],dbest[q])){ibest[q]=inter;dbest[q]=den;bj[q]=c*CH+jj;}
                    if (better(inter,den,tiN[jj],tdN[jj])){tiN[jj]=inter;tdN[jj]=den;tdd[jj]=d;}
                }
            }
        }
        // per-truth reduce: exact f32 iou per candidate, fmax+ballot (lane order == d order)
#pragma unroll
        for (int jj=0;jj<CH;++jj){
            float tbv=tiN[jj]/tdN[jj];          // IEEE: reference-exact key values
            float m=tbv;
#pragma unroll
            for (int off=32;off>=1;off>>=1) m=fmaxf(m,__shfl_xor(m,off,64));
            unsigned long long msk=__ballot(tbv==m);
            int lead=__builtin_ctzll(msk);
            int dwin=__shfl(tdd[jj],lead,64);
            if (lane==0){
                s_wk[wv][c*CH+jj]=(m>=0.f)
                    ?(((unsigned long long)__float_as_uint(m)<<32)
                      |(unsigned long long)(0xFFFFFFFFu-(unsigned)dwin))
                    :0ull;
            }
        }
    }
    __syncthreads();
    if (tid<NOBJ){
        unsigned long long m=s_wk[0][tid];
        for (int w=1;w<NW;++w){unsigned long long o=s_wk[w][tid]; if(o>m)m=o;}
        g_kpart[((size_t)b*NBA+spl)*NOBJ+tid]=m;
    }

    // CE/L1 phase (no-override view)
    float np=0.f,sl=0.f,sc=0.f;
    if (vld){
        const size_t cbase=((size_t)b*ND+d0)/2;
        float4 cfa=reinterpret_cast<const float4*>(conf_data)[cbase+tid*2];
        float4 cfb=reinterpret_cast<const float4*>(conf_data)[cbase+tid*2+1];
        float raw[PPT];
#pragma unroll
        for (int q=0;q<PPT;++q){
            const int d=d0+tid*PPT+q;
            float cfx=(q==0)?cfa.x:(q==1)?cfa.z:(q==2)?cfb.x:cfb.z;
            float cfy=(q==0)?cfa.y:(q==1)?cfa.w:(q==2)?cfb.y:cfb.w;
            float l=lse2(cfx,cfy);
            float bovq=ibest[q]/dbest[q];       // IEEE: reference-exact threshold
            bool pos=!(bovq<0.5f);
            int jb=bj[q];
            int lab=pos?((int)s_lab[jb]+1):0;
            float cev=l-(lab>=1?cfy:cfx);
            raw[q]=pos?-cev:cev;
            atomicAdd(&s_wh[wv*256+(int)(__float_as_uint(fmaxf(raw[q],0.f))>>24)],1);
            if (pos){
                np+=1.f; sc+=cev;
                float4 p=dbox4[d];
                float4 ldv=reinterpret_cast<const float4*>(loc_data)[(size_t)b*ND+d];
                sl+=sl1_enc(p,s_tx1[jb],s_ty1[jb],s_tx2[jb],s_ty2[jb],ldv);
            }
        }
        float4 st; st.x=raw[0];st.y=raw[1];st.z=raw[2];st.w=raw[3];
        g_ce4[((size_t)b*ND+d0)/4+tid]=st;
    }
#pragma unroll
    for (int off=32;off>=1;off>>=1){
        np+=__shfl_xor(np,off,64); sl+=__shfl_xor(sl,off,64); sc+=__shfl_xor(sc,off,64);
    }
    if (lane==0){s_r1[wv]=np;s_r2[wv]=sl;s_r3[wv]=sc;}
    __syncthreads();
    if (tid==0){
        float a=0.f,bb=0.f,cc=0.f;
        for (int w=0;w<NW;++w){a+=s_r1[w];bb+=s_r2[w];cc+=s_r3[w];}
        g_bp[(b*NBA+spl)*3+0]=a;
        g_bp[(b*NBA+spl)*3+1]=bb;
        g_bp[(b*NBA+spl)*3+2]=cc;
    }
    if (tid<256){
        int s=0;
        for (int w=0;w<NW;++w) s+=s_wh[w*256+tid];
        g_hist[(size_t)(b*NBA+spl)*256+tid]=s;
    }
}

// ---------------- K2: merge + corrections + radix select + fused finisher ----------------
__global__ __launch_bounds__(BLK2) void k2(const float* __restrict__ loc_data,
                                           const float* __restrict__ conf_data,
                                           const float* __restrict__ dbox,
                                           const float* __restrict__ targets,
                                           float* __restrict__ out){
    __shared__ float4 s_ce4[ND4];
    __shared__ unsigned long long s_kmm[NOBJ*NBA];   // 450
    __shared__ unsigned int s_dj[NOBJ];
    __shared__ float s_tx1[NOBJ],s_ty1[NOBJ],s_tx2[NOBJ],s_ty2[NOBJ],s_ta[NOBJ],s_lab[NOBJ];
    __shared__ int   s_hist[256];
    __shared__ int   s_wh[NW2*256];
    __shared__ float s_bpl[NBA*3];
    __shared__ float s_rf[NW2]; __shared__ int s_ri[NW2];
    __shared__ int   s_wt[4];
    __shared__ float s_dnp,s_dsl,s_dsc;
    __shared__ int   s_sel,s_krem,s_kk,s_last;
    float* s_ce=(float*)s_ce4;

    const int b=blockIdx.x, tid=threadIdx.x, lane=tid&63, wv=tid>>6;

    if (tid<NOBJ){
        const float* t=targets+(b*NOBJ+tid)*5;
        float x1=t[0],y1=t[1],x2=t[2],y2=t[3];
        s_tx1[tid]=x1;s_ty1[tid]=y1;s_tx2[tid]=x2;s_ty2[tid]=y2;
        s_ta[tid]=__fmul_rn(__fsub_rn(x2,x1),__fsub_rn(y2,y1));
        s_lab[tid]=t[4];
    }
    if (tid<NOBJ*NBA){
        int j=tid/NBA, s=tid-j*NBA;
        s_kmm[tid]=g_kpart[((size_t)b*NBA+s)*NOBJ+j];
    }
    for (int i=tid;i<ND4;i+=BLK2) s_ce4[i]=g_ce4[(size_t)b*ND4+i];
    if (tid<256){
        int s=0;
        for (int sp=0;sp<NBA;++sp) s+=g_hist[(size_t)(b*NBA+sp)*256+tid];
        s_hist[tid]=s;
    }
    if (tid<NBA*3) s_bpl[tid]=g_bp[b*NBA*3+tid];
    __syncthreads();
    if (tid<NOBJ){
        unsigned long long m=s_kmm[tid*NBA];
        for (int s=1;s<NBA;++s){unsigned long long o=s_kmm[tid*NBA+s]; if(o>m)m=o;}
        s_dj[tid]=0xFFFFFFFFu-(unsigned)(m&0xFFFFFFFFull);
    }
    __syncthreads();

    // override corrections (<=50 priors forced positive, last-write-wins)
    float dnp=0.f,dsl=0.f,dsc=0.f;
    if (tid<NOBJ){
        unsigned d=s_dj[tid]; bool win=true;
        for (int j2=tid+1;j2<NOBJ;++j2) if (s_dj[j2]==d){win=false;break;}
        if (win){
            float4 p=reinterpret_cast<const float4*>(dbox)[d];
            float hw=__fmul_rn(0.5f,p.z), hh2=__fmul_rn(0.5f,p.w);
            float ppx1=__fsub_rn(p.x,hw),ppy1=__fsub_rn(p.y,hh2);
            float ppx2=__fadd_rn(p.x,hw),ppy2=__fadd_rn(p.y,hh2);
            float ppa=__fmul_rn(p.z,p.w);
            float ib=-1.f,db=1.f; int jb=0;
            for (int j=0;j<NOBJ;++j){           // same sequential cross-mul tracker as k1
                float inter,den;
                iou_parts(ppx1,ppy1,ppx2,ppy2,ppa,
                          s_tx1[j],s_ty1[j],s_tx2[j],s_ty2[j],s_ta[j],inter,den);
                if (better(inter,den,ib,db)){ib=inter;db=den;jb=j;}
            }
            float bov=ib/db;
            bool oldpos=!(bov<0.5f);
            float2 cf=reinterpret_cast<const float2*>(conf_data)[(size_t)b*ND+d];
            float l=lse2(cf.x,cf.y);
            float4 ldv=reinterpret_cast<const float4*>(loc_data)[(size_t)b*ND+d];
            int labN=(int)s_lab[tid]+1;
            float ceN=l-(labN>=1?cf.y:cf.x);
            dsc+=ceN; dsl+=sl1_enc(p,s_tx1[tid],s_ty1[tid],s_tx2[tid],s_ty2[tid],ldv);
            if (oldpos){
                int labO=(int)s_lab[jb]+1;
                float ceO=l-(labO>=1?cf.y:cf.x);
                dsc-=ceO; dsl-=sl1_enc(p,s_tx1[jb],s_ty1[jb],s_tx2[jb],s_ty2[jb],ldv);
            } else dnp+=1.f;
            float oldraw=s_ce[d];
            atomicAdd(&s_hist[(int)(__float_as_uint(fmaxf(oldraw,0.f))>>24)],-1);
            atomicAdd(&s_hist[0],1);
            s_ce[d]=-ceN;
        }
    }
    if (wv==0){
#pragma unroll
        for (int off=32;off>=1;off>>=1){
            dnp+=__shfl_xor(dnp,off,64); dsl+=__shfl_xor(dsl,off,64); dsc+=__shfl_xor(dsc,off,64);
        }
        if (lane==0){s_dnp=dnp;s_dsl=dsl;s_dsc=dsc;}
    }
    __syncthreads();
    if (tid==0){
        float np=s_dnp, sl=s_dsl, sc=s_dsc;
        for (int i=0;i<NBA;++i){np+=s_bpl[i*3];sl+=s_bpl[i*3+1];sc+=s_bpl[i*3+2];}
        int npi=(int)np; int k=npi*3; if(k<20)k=20; if(k>ND)k=ND;
        s_kk=k;
        g_part[b*5+0]=np; g_part[b*5+1]=sl; g_part[b*5+2]=sc; g_part[b*5+3]=(float)k;
    }
    __syncthreads();
    const int k=s_kk;

    // radix select: pass 1 free from histogram; passes 2-3 scan LDS
    unsigned prefix=0u,pmask=0u; int krem=k;
    for (int p=0;p<3;++p){
        const int shift=24-p*8;
        int cnt=0;
        if (p==0){
            if (tid<256) cnt=s_hist[tid];
        } else {
            for (int i=tid;i<NW2*256;i+=BLK2) s_wh[i]=0;
            __syncthreads();
            for (int it=0;it<ITER2;++it){
                int d=tid+it*BLK2;
                if (d<ND){
                    unsigned vb=__float_as_uint(fmaxf(s_ce[d],0.f));
                    if ((vb&pmask)==prefix)
                        atomicAdd(&s_wh[wv*256+(int)((vb>>shift)&255u)],1);
                }
            }
            __syncthreads();
            if (tid<256){
                for (int w=0;w<NW2;++w) cnt+=s_wh[w*256+tid];
            }
        }
        int S=cnt,add=0;
        if (tid<256){
#pragma unroll
            for (int off=1;off<64;off<<=1){
                int t=__shfl_down(S,off,64);
                if (lane+off<64) S+=t;
            }
            if (lane==0) s_wt[wv]=S;
        }
        __syncthreads();
        if (tid<256){
            for (int w=wv+1;w<4;++w) add+=s_wt[w];
            S+=add;
            int Snext=__shfl_down(S,1,64);
            if (lane==63) Snext=add;
            if (S>=krem && Snext<krem){s_sel=tid;s_krem=krem-(S-cnt);}
        }
        __syncthreads();
        prefix|=((unsigned)s_sel)<<shift;
        pmask|=255u<<shift;
        krem=s_krem;
        __syncthreads();
    }
    const float T=__uint_as_float(prefix);

    int cgt=0; float sgt=0.f;
    for (int it=0;it<ITER2;++it){
        int d=tid+it*BLK2;
        if (d<ND){
            float v=fmaxf(s_ce[d],0.f);
            if (v>T){cgt++;sgt+=v;}
        }
    }
#pragma unroll
    for (int off=32;off>=1;off>>=1){cgt+=__shfl_xor(cgt,off,64);sgt+=__shfl_xor(sgt,off,64);}
    if (lane==0){s_ri[wv]=cgt;s_rf[wv]=sgt;}
    __syncthreads();
    if (tid==0){
        int cg=0; float sg=0.f;
        for (int w=0;w<NW2;++w){cg+=s_ri[w];sg+=s_rf[w];}
        int need=k-cg;
        float stk=sg+(float)need*T;
        if (!(T>0.f)&&need>0){
            int taken=0;
            for (int d=0;d<ND&&taken<need;++d){
                float r2=s_ce[d];
                if (!(r2>0.f)){stk+=fabsf(r2);++taken;}
            }
        }
        g_part[b*5+4]=stk;
    }

    if (tid==0){__threadfence(); int old=atomicAdd(&g_done,1); s_last=(old==NB-1)?1:0;}
    __syncthreads();
    if (s_last&&tid<NB){
        __threadfence();
        volatile float* gp=g_part;
        float np=gp[tid*5+0],sl=gp[tid*5+1],sc=gp[tid*5+2],kk=gp[tid*5+3],st=gp[tid*5+4];
#pragma unroll
        for (int off=32;off>=1;off>>=1){
            np+=__shfl_xor(np,off,64);sl+=__shfl_xor(sl,off,64);
            sc+=__shfl_xor(sc,off,64);kk+=__shfl_xor(kk,off,64);st+=__shfl_xor(st,off,64);
        }
        if (tid==0){
            float loss_l=(np>0.f)?sl/(4.f*np):0.f;
            float lcp=(np>0.f)?sc/np:0.f;
            float lcn=(kk>0.f)?st/kk:0.f;
            out[0]=loss_l;out[1]=lcp+lcn;out[2]=lcp;out[3]=lcn;
        }
    }
}

extern "C" void kernel_launch(void* const* d_in, const int* in_sizes, int n_in,
                              void* d_out, int out_size, void* d_ws, size_t ws_size,
                              hipStream_t stream) {
    const float* loc     = (const float*)d_in[0];
    const float* conf    = (const float*)d_in[1];
    const float* dboxp   = (const float*)d_in[2];
    const float* targets = (const float*)d_in[3];
    float* out = (float*)d_out;

    k1<<<NB*NBA, BLK, 0, stream>>>(loc, conf, dboxp, targets);
    k2<<<NB, BLK2, 0, stream>>>(loc, conf, dboxp, targets, out);
}

// Round 10
// 148.849 us; speedup vs baseline: 1.0056x; 1.0056x over previous
//
#include <hip/hip_runtime.h>

#define NB     64
#define NOBJ   50
#define ND     8732
#define BLK    128
#define NW     (BLK/64)              // 2 waves
#define PPT    4
#define PRB    (BLK*PPT)             // 512 priors per block
#define NBA    18                    // 17*512=8704, tail 28 (28%4==0)
#define CH     10
#define NCH    5
#define BLK2   1024
#define NW2    (BLK2/64)
#define ITER2  ((ND+BLK2-1)/BLK2)    // 9
#define ND4    (ND/4)

// device scratch — every element rewritten each launch (graph-replay safe, deterministic)
__device__ float              g_part[NB*5];
__device__ float4             g_ce4[(size_t)NB*ND4];       // signed ce_mined (pos -> -ce_pos)
__device__ unsigned long long g_kpart[NB*NBA*NOBJ];        // per-split per-truth keys
__device__ int                g_hist[(size_t)NB*NBA*256];
__device__ float              g_bp[NB*NBA*3];
__device__ int                g_done;

// division-free IoU pieces; bit-identical in k1 and k2-correction
__device__ __forceinline__ void iou_parts(float px1,float py1,float px2,float py2,float pa,
                                          float tx1,float ty1,float tx2,float ty2,float ta,
                                          float& inter,float& den){
    float ltx=fmaxf(tx1,px1), lty=fmaxf(ty1,py1);
    float rbx=fminf(tx2,px2), rby=fminf(ty2,py2);
    float ww=fmaxf(__fsub_rn(rbx,ltx),0.f), hh=fmaxf(__fsub_rn(rby,lty),0.f);
    inter=__fmul_rn(ww,hh);
    den=__fsub_rn(__fadd_rn(ta,pa),inter);
}
// strict "new beats old" under cross-multiplication (dens > 0)
__device__ __forceinline__ bool better(float iN,float dN,float iO,float dO){
    return __fmul_rn(iN,dO) > __fmul_rn(iO,dN);
}
__device__ __forceinline__ float lse2(float x0,float x1){
    float m=fmaxf(x0,x1);
    return m+__logf(__expf(x0-m)+__expf(x1-m));
}
__device__ __forceinline__ float sl1_enc(float4 p,float tx1,float ty1,float tx2,float ty2,float4 ld){
    float g0=((tx1+tx2)*0.5f-p.x)/(0.1f*p.z);
    float g1=((ty1+ty2)*0.5f-p.y)/(0.1f*p.w);
    float g2=__logf((tx2-tx1)/p.z)*5.0f;
    float g3=__logf((ty2-ty1)/p.w)*5.0f;
    float t0=fabsf(ld.x-g0),t1=fabsf(ld.y-g1),t2=fabsf(ld.z-g2),t3=fabsf(ld.w-g3);
    return (t0<1.f?0.5f*t0*t0:t0-0.5f)+(t1<1.f?0.5f*t1*t1:t1-0.5f)
          +(t2<1.f?0.5f*t2*t2:t2-0.5f)+(t3<1.f?0.5f*t3*t3:t3-0.5f);
}

// ---------------- K1: division-free joint match + CE/L1/hist ----------------
__global__ __launch_bounds__(BLK) void k1(const float* __restrict__ loc_data,
                                          const float* __restrict__ conf_data,
                                          const float* __restrict__ dbox,
                                          const float* __restrict__ targets){
    __shared__ float s_tx1[NOBJ],s_ty1[NOBJ],s_tx2[NOBJ],s_ty2[NOBJ],s_ta[NOBJ],s_lab[NOBJ];
    __shared__ unsigned long long s_wk[NW][NOBJ];
    __shared__ int   s_wh[NW*256];
    __shared__ float s_r1[NW],s_r2[NW],s_r3[NW];

    const int blk=blockIdx.x, b=blk/NBA, spl=blk%NBA;
    const int tid=threadIdx.x, lane=tid&63, wv=tid>>6;
    const float4* dbox4=reinterpret_cast<const float4*>(dbox);
    if (blk==0 && tid==0) g_done=0;

    if (tid<NOBJ){
        const float* t=targets+(b*NOBJ+tid)*5;
        float x1=t[0],y1=t[1],x2=t[2],y2=t[3];
        s_tx1[tid]=x1;s_ty1[tid]=y1;s_tx2[tid]=x2;s_ty2[tid]=y2;
        s_ta[tid]=__fmul_rn(__fsub_rn(x2,x1),__fsub_rn(y2,y1));
        s_lab[tid]=t[4];
    }
    for (int i=tid;i<NW*256;i+=BLK) s_wh[i]=0;
    __syncthreads();

    const int d0=spl*PRB;
    const int cnt=(ND-d0<PRB)?(ND-d0):PRB;   // 512 or 28, both %4==0
    const bool vld=(tid*PPT)<cnt;
    float px1[PPT],py1[PPT],px2[PPT],py2[PPT],pa[PPT];
    float ibest[PPT],dbest[PPT]; int bj[PPT];
#pragma unroll
    for (int q=0;q<PPT;++q){
        ibest[q]=-1.f; dbest[q]=1.f; bj[q]=0;
        px1[q]=py1[q]=px2[q]=py2[q]=pa[q]=0.f;
        if (vld){
            float4 p=dbox4[d0+tid*PPT+q];
            float hw=__fmul_rn(0.5f,p.z), hh=__fmul_rn(0.5f,p.w);
            px1[q]=__fsub_rn(p.x,hw); py1[q]=__fsub_rn(p.y,hh);
            px2[q]=__fadd_rn(p.x,hw); py2[q]=__fadd_rn(p.y,hh);
            pa[q]=__fmul_rn(p.z,p.w);
        }
    }

    for (int c=0;c<NCH;++c){
        float tx1c[CH],ty1c[CH],tx2c[CH],ty2c[CH],tac[CH];
#pragma unroll
        for (int jj=0;jj<CH;++jj){
            int j=c*CH+jj;
            tx1c[jj]=s_tx1[j]; ty1c[jj]=s_ty1[j];
            tx2c[jj]=s_tx2[j]; ty2c[jj]=s_ty2[j];
            tac[jj]=s_ta[j];
        }
        float tiN[CH],tdN[CH]; int tdd[CH];
#pragma unroll
        for (int jj=0;jj<CH;++jj){tiN[jj]=-1.f;tdN[jj]=1.f;tdd[jj]=0;}

        if (vld){
#pragma unroll
            for (int q=0;q<PPT;++q){
                const int d=d0+tid*PPT+q;
#pragma unroll
                for (int jj=0;jj<CH;++jj){
                    float inter,den;
                    iou_parts(px1[q],py1[q],px2[q],py2[q],pa[q],
                              tx1c[jj],ty1c[jj],tx2c[jj],ty2c[jj],tac[jj],inter,den);
                    if (better(inter,den,ibest[q],dbest[q])){ibest[q]=inter;dbest[q]=den;bj[q]=c*CH+jj;}
                    if (better(inter,den,tiN[jj],tdN[jj])){tiN[jj]=inter;tdN[jj]=den;tdd[jj]=d;}
                }
            }
        }
        // per-truth reduce: exact f32 iou per candidate, fmax+ballot (lane order == d order)
#pragma unroll
        for (int jj=0;jj<CH;++jj){
            float tbv=tiN[jj]/tdN[jj];          // IEEE: reference-exact key values
            float m=tbv;
#pragma unroll
            for (int off=32;off>=1;off>>=1) m=fmaxf(m,__shfl_xor(m,off,64));
            unsigned long long msk=__ballot(tbv==m);
            int lead=__builtin_ctzll(msk);
            int dwin=__shfl(tdd[jj],lead,64);
            if (lane==0){
                s_wk[wv][c*CH+jj]=(m>=0.f)
                    ?(((unsigned long long)__float_as_uint(m)<<32)
                      |(unsigned long long)(0xFFFFFFFFu-(unsigned)dwin))
                    :0ull;
            }
        }
    }
    __syncthreads();
    if (tid<NOBJ){
        unsigned long long m=s_wk[0][tid];
        for (int w=1;w<NW;++w){unsigned long long o=s_wk[w][tid]; if(o>m)m=o;}
        g_kpart[((size_t)b*NBA+spl)*NOBJ+tid]=m;
    }

    // CE/L1 phase (no-override view)
    float np=0.f,sl=0.f,sc=0.f;
    if (vld){
        const size_t cbase=((size_t)b*ND+d0)/2;
        float4 cfa=reinterpret_cast<const float4*>(conf_data)[cbase+tid*2];
        float4 cfb=reinterpret_cast<const float4*>(conf_data)[cbase+tid*2+1];
        float raw[PPT];
#pragma unroll
        for (int q=0;q<PPT;++q){
            const int d=d0+tid*PPT+q;
            float cfx=(q==0)?cfa.x:(q==1)?cfa.z:(q==2)?cfb.x:cfb.z;
            float cfy=(q==0)?cfa.y:(q==1)?cfa.w:(q==2)?cfb.y:cfb.w;
            float l=lse2(cfx,cfy);
            float bovq=ibest[q]/dbest[q];       // IEEE: reference-exact threshold
            bool pos=!(bovq<0.5f);
            int jb=bj[q];
            int lab=pos?((int)s_lab[jb]+1):0;
            float cev=l-(lab>=1?cfy:cfx);
            raw[q]=pos?-cev:cev;
            atomicAdd(&s_wh[wv*256+(int)(__float_as_uint(fmaxf(raw[q],0.f))>>24)],1);
            if (pos){
                np+=1.f; sc+=cev;
                float4 p=dbox4[d];
                float4 ldv=reinterpret_cast<const float4*>(loc_data)[(size_t)b*ND+d];
                sl+=sl1_enc(p,s_tx1[jb],s_ty1[jb],s_tx2[jb],s_ty2[jb],ldv);
            }
        }
        float4 st; st.x=raw[0];st.y=raw[1];st.z=raw[2];st.w=raw[3];
        g_ce4[((size_t)b*ND+d0)/4+tid]=st;
    }
#pragma unroll
    for (int off=32;off>=1;off>>=1){
        np+=__shfl_xor(np,off,64); sl+=__shfl_xor(sl,off,64); sc+=__shfl_xor(sc,off,64);
    }
    if (lane==0){s_r1[wv]=np;s_r2[wv]=sl;s_r3[wv]=sc;}
    __syncthreads();
    if (tid==0){
        float a=0.f,bb=0.f,cc=0.f;
        for (int w=0;w<NW;++w){a+=s_r1[w];bb+=s_r2[w];cc+=s_r3[w];}
        g_bp[(b*NBA+spl)*3+0]=a;
        g_bp[(b*NBA+spl)*3+1]=bb;
        g_bp[(b*NBA+spl)*3+2]=cc;
    }
    if (tid<BLK){
        for (int i=tid;i<256;i+=BLK){
            int s=0;
            for (int w=0;w<NW;++w) s+=s_wh[w*256+i];
            g_hist[(size_t)(b*NBA+spl)*256+i]=s;
        }
    }
}

// ---------------- K2: merge + corrections + radix select + fused finisher ----------------
__global__ __launch_bounds__(BLK2) void k2(const float* __restrict__ loc_data,
                                           const float* __restrict__ conf_data,
                                           const float* __restrict__ dbox,
                                           const float* __restrict__ targets,
                                           float* __restrict__ out){
    __shared__ float4 s_ce4[ND4];
    __shared__ unsigned long long s_kmm[NOBJ*NBA];   // 900
    __shared__ unsigned int s_dj[NOBJ];
    __shared__ float s_tx1[NOBJ],s_ty1[NOBJ],s_tx2[NOBJ],s_ty2[NOBJ],s_ta[NOBJ],s_lab[NOBJ];
    __shared__ int   s_hist[256];
    __shared__ int   s_wh[NW2*256];
    __shared__ float s_bpl[NBA*3];
    __shared__ float s_rf[NW2]; __shared__ int s_ri[NW2];
    __shared__ int   s_wt[4];
    __shared__ float s_dnp,s_dsl,s_dsc;
    __shared__ int   s_sel,s_krem,s_kk,s_last;
    float* s_ce=(float*)s_ce4;

    const int b=blockIdx.x, tid=threadIdx.x, lane=tid&63, wv=tid>>6;

    if (tid<NOBJ){
        const float* t=targets+(b*NOBJ+tid)*5;
        float x1=t[0],y1=t[1],x2=t[2],y2=t[3];
        s_tx1[tid]=x1;s_ty1[tid]=y1;s_tx2[tid]=x2;s_ty2[tid]=y2;
        s_ta[tid]=__fmul_rn(__fsub_rn(x2,x1),__fsub_rn(y2,y1));
        s_lab[tid]=t[4];
    }
    if (tid<NOBJ*NBA){
        int j=tid/NBA, s=tid-j*NBA;
        s_kmm[tid]=g_kpart[((size_t)b*NBA+s)*NOBJ+j];
    }
    for (int i=tid;i<ND4;i+=BLK2) s_ce4[i]=g_ce4[(size_t)b*ND4+i];
    if (tid<256){
        int s=0;
        for (int sp=0;sp<NBA;++sp) s+=g_hist[(size_t)(b*NBA+sp)*256+tid];
        s_hist[tid]=s;
    }
    if (tid<NBA*3) s_bpl[tid]=g_bp[b*NBA*3+tid];
    __syncthreads();
    if (tid<NOBJ){
        unsigned long long m=s_kmm[tid*NBA];
        for (int s=1;s<NBA;++s){unsigned long long o=s_kmm[tid*NBA+s]; if(o>m)m=o;}
        s_dj[tid]=0xFFFFFFFFu-(unsigned)(m&0xFFFFFFFFull);
    }
    __syncthreads();

    // override corrections (<=50 priors forced positive, last-write-wins)
    float dnp=0.f,dsl=0.f,dsc=0.f;
    if (tid<NOBJ){
        unsigned d=s_dj[tid]; bool win=true;
        for (int j2=tid+1;j2<NOBJ;++j2) if (s_dj[j2]==d){win=false;break;}
        if (win){
            float4 p=reinterpret_cast<const float4*>(dbox)[d];
            float hw=__fmul_rn(0.5f,p.z), hh2=__fmul_rn(0.5f,p.w);
            float ppx1=__fsub_rn(p.x,hw),ppy1=__fsub_rn(p.y,hh2);
            float ppx2=__fadd_rn(p.x,hw),ppy2=__fadd_rn(p.y,hh2);
            float ppa=__fmul_rn(p.z,p.w);
            float ib=-1.f,db=1.f; int jb=0;
            for (int j=0;j<NOBJ;++j){           // same sequential cross-mul tracker as k1
                float inter,den;
                iou_parts(ppx1,ppy1,ppx2,ppy2,ppa,
                          s_tx1[j],s_ty1[j],s_tx2[j],s_ty2[j],s_ta[j],inter,den);
                if (better(inter,den,ib,db)){ib=inter;db=den;jb=j;}
            }
            float bov=ib/db;
            bool oldpos=!(bov<0.5f);
            float2 cf=reinterpret_cast<const float2*>(conf_data)[(size_t)b*ND+d];
            float l=lse2(cf.x,cf.y);
            float4 ldv=reinterpret_cast<const float4*>(loc_data)[(size_t)b*ND+d];
            int labN=(int)s_lab[tid]+1;
            float ceN=l-(labN>=1?cf.y:cf.x);
            dsc+=ceN; dsl+=sl1_enc(p,s_tx1[tid],s_ty1[tid],s_tx2[tid],s_ty2[tid],ldv);
            if (oldpos){
                int labO=(int)s_lab[jb]+1;
                float ceO=l-(labO>=1?cf.y:cf.x);
                dsc-=ceO; dsl-=sl1_enc(p,s_tx1[jb],s_ty1[jb],s_tx2[jb],s_ty2[jb],ldv);
            } else dnp+=1.f;
            float oldraw=s_ce[d];
            atomicAdd(&s_hist[(int)(__float_as_uint(fmaxf(oldraw,0.f))>>24)],-1);
            atomicAdd(&s_hist[0],1);
            s_ce[d]=-ceN;
        }
    }
    if (wv==0){
#pragma unroll
        for (int off=32;off>=1;off>>=1){
            dnp+=__shfl_xor(dnp,off,64); dsl+=__shfl_xor(dsl,off,64); dsc+=__shfl_xor(dsc,off,64);
        }
        if (lane==0){s_dnp=dnp;s_dsl=dsl;s_dsc=dsc;}
    }
    __syncthreads();
    if (tid==0){
        float np=s_dnp, sl=s_dsl, sc=s_dsc;
        for (int i=0;i<NBA;++i){np+=s_bpl[i*3];sl+=s_bpl[i*3+1];sc+=s_bpl[i*3+2];}
        int npi=(int)np; int k=npi*3; if(k<20)k=20; if(k>ND)k=ND;
        s_kk=k;
        g_part[b*5+0]=np; g_part[b*5+1]=sl; g_part[b*5+2]=sc; g_part[b*5+3]=(float)k;
    }
    __syncthreads();
    const int k=s_kk;

    // radix select: pass 1 free from histogram; passes 2-3 scan LDS
    unsigned prefix=0u,pmask=0u; int krem=k;
    for (int p=0;p<3;++p){
        const int shift=24-p*8;
        int cnt=0;
        if (p==0){
            if (tid<256) cnt=s_hist[tid];
        } else {
            for (int i=tid;i<NW2*256;i+=BLK2) s_wh[i]=0;
            __syncthreads();
            for (int it=0;it<ITER2;++it){
                int d=tid+it*BLK2;
                if (d<ND){
                    unsigned vb=__float_as_uint(fmaxf(s_ce[d],0.f));
                    if ((vb&pmask)==prefix)
                        atomicAdd(&s_wh[wv*256+(int)((vb>>shift)&255u)],1);
                }
            }
            __syncthreads();
            if (tid<256){
                for (int w=0;w<NW2;++w) cnt+=s_wh[w*256+tid];
            }
        }
        int S=cnt,add=0;
        if (tid<256){
#pragma unroll
            for (int off=1;off<64;off<<=1){
                int t=__shfl_down(S,off,64);
                if (lane+off<64) S+=t;
            }
            if (lane==0) s_wt[wv]=S;
        }
        __syncthreads();
        if (tid<256){
            for (int w=wv+1;w<4;++w) add+=s_wt[w];
            S+=add;
            int Snext=__shfl_down(S,1,64);
            if (lane==63) Snext=add;
            if (S>=krem && Snext<krem){s_sel=tid;s_krem=krem-(S-cnt);}
        }
        __syncthreads();
        prefix|=((unsigned)s_sel)<<shift;
        pmask|=255u<<shift;
        krem=s_krem;
        __syncthreads();
    }
    const float T=__uint_as_float(prefix);

    int cgt=0; float sgt=0.f;
    for (int it=0;it<ITER2;++it){
        int d=tid+it*BLK2;
        if (d<ND){
            float v=fmaxf(s_ce[d],0.f);
            if (v>T){cgt++;sgt+=v;}
        }
    }
#pragma unroll
    for (int off=32;off>=1;off>>=1){cgt+=__shfl_xor(cgt,off,64);sgt+=__shfl_xor(sgt,off,64);}
    if (lane==0){s_ri[wv]=cgt;s_rf[wv]=sgt;}
    __syncthreads();
    if (tid==0){
        int cg=0; float sg=0.f;
        for (int w=0;w<NW2;++w){cg+=s_ri[w];sg+=s_rf[w];}
        int need=k-cg;
        float stk=sg+(float)need*T;
        if (!(T>0.f)&&need>0){
            int taken=0;
            for (int d=0;d<ND&&taken<need;++d){
                float r2=s_ce[d];
                if (!(r2>0.f)){stk+=fabsf(r2);++taken;}
            }
        }
        g_part[b*5+4]=stk;
    }

    if (tid==0){__threadfence(); int old=atomicAdd(&g_done,1); s_last=(old==NB-1)?1:0;}
    __syncthreads();
    if (s_last&&tid<NB){
        __threadfence();
        volatile float* gp=g_part;
        float np=gp[tid*5+0],sl=gp[tid*5+1],sc=gp[tid*5+2],kk=gp[tid*5+3],st=gp[tid*5+4];
#pragma unroll
        for (int off=32;off>=1;off>>=1){
            np+=__shfl_xor(np,off,64);sl+=__shfl_xor(sl,off,64);
            sc+=__shfl_xor(sc,off,64);kk+=__shfl_xor(kk,off,64);st+=__shfl_xor(st,off,64);
        }
        if (tid==0){
            float loss_l=(np>0.f)?sl/(4.f*np):0.f;
            float lcp=(np>0.f)?sc/np:0.f;
            float lcn=(kk>0.f)?st/kk:0.f;
            out[0]=loss_l;out[1]=lcp+lcn;out[2]=lcp;out[3]=lcn;
        }
    }
}

extern "C" void kernel_launch(void* const* d_in, const int* in_sizes, int n_in,
                              void* d_out, int out_size, void* d_ws, size_t ws_size,
                              hipStream_t stream) {
    const float* loc     = (const float*)d_in[0];
    const float* conf    = (const float*)d_in[1];
    const float* dboxp   = (const float*)d_in[2];
    const float* targets = (const float*)d_in[3];
    float* out = (float*)d_out;

    k1<<<NB*NBA, BLK, 0, stream>>>(loc, conf, dboxp, targets);
    k2<<<NB, BLK2, 0, stream>>>(loc, conf, dboxp, targets, out);
}

// Round 11
// 124.382 us; speedup vs baseline: 1.2034x; 1.1967x over previous
//
#include <hip/hip_runtime.h>

#define NB     64
#define NOBJ   50
#define ND     8732
#define PPT    3
#define BLK1   256
#define PRB    (BLK1*PPT)            // 768 priors / k1 block
#define NSPLIT 12                    // ceil(8732/768)
#define NW1    (BLK1/64)             // 4
#define NPART  (NSPLIT*NW1)          // 48 key partials per batch
#define CHUNK  10
#define NCHUNK 5
#define BLK2   1024
#define NW2    (BLK2/64)             // 16
#define ITER2  ((ND+BLK2-1)/BLK2)    // 9
#define ND4    (ND/4)                // 2183

// device scratch — every element rewritten each launch (graph-replay safe, deterministic)
__device__ float              g_part[NB*5];
__device__ float4             g_ce4[(size_t)NB*ND4];          // signed ce_mined (pos -> -ce_pos)
__device__ unsigned long long g_keys[(size_t)NB*NSPLIT*NW1*NOBJ];
__device__ int                g_hist[(size_t)NB*NSPLIT*256];
__device__ float              g_bp[NB*NSPLIT*3];              // per-split npos/sl1/scep
__device__ int                g_done;

// bit-exact IoU (contraction-proof: used by k1 main loop AND k2 corrections)
__device__ __forceinline__ float iou_rn(float px1,float py1,float px2,float py2,float pa,
                                        float tx1,float ty1,float tx2,float ty2,float ta){
    float ltx=fmaxf(tx1,px1), lty=fmaxf(ty1,py1);
    float rbx=fminf(tx2,px2), rby=fminf(ty2,py2);
    float ww=fmaxf(__fsub_rn(rbx,ltx),0.f), hh=fmaxf(__fsub_rn(rby,lty),0.f);
    float inter=__fmul_rn(ww,hh);
    return __fdividef(inter, __fsub_rn(__fadd_rn(ta,pa),inter));
}
__device__ __forceinline__ float lse2(float x0,float x1){
    float m=fmaxf(x0,x1);
    return m+__logf(__expf(x0-m)+__expf(x1-m));
}
__device__ __forceinline__ float sl1_enc(float4 p,float tx1,float ty1,float tx2,float ty2,float4 ld){
    float g0=((tx1+tx2)*0.5f-p.x)/(0.1f*p.z);
    float g1=((ty1+ty2)*0.5f-p.y)/(0.1f*p.w);
    float g2=__logf((tx2-tx1)/p.z)*5.0f;
    float g3=__logf((ty2-ty1)/p.w)*5.0f;
    float t0=fabsf(ld.x-g0),t1=fabsf(ld.y-g1),t2=fabsf(ld.z-g2),t3=fabsf(ld.w-g3);
    return (t0<1.f?0.5f*t0*t0:t0-0.5f)+(t1<1.f?0.5f*t1*t1:t1-0.5f)
          +(t2<1.f?0.5f*t2*t2:t2-0.5f)+(t3<1.f?0.5f*t3*t3:t3-0.5f);
}

// ---------------- K1: IoU + argmaxes + CE/L1/hist (no-override view) ----------------
__global__ __launch_bounds__(BLK1) void k1(const float* __restrict__ loc_data,
                                           const float* __restrict__ conf_data,
                                           const float* __restrict__ dbox,
                                           const float* __restrict__ targets){
    __shared__ float s_tx1[NOBJ],s_ty1[NOBJ],s_tx2[NOBJ],s_ty2[NOBJ],s_ta[NOBJ],s_lab[NOBJ];
    __shared__ int   s_wh[NW1*256];
    __shared__ float s_r1[NW1],s_r2[NW1],s_r3[NW1];
    const int blk=blockIdx.x, b=blk/NSPLIT, spl=blk%NSPLIT;
    const int tid=threadIdx.x, lane=tid&63, wv=tid>>6;
    if (blk==0 && tid==0) g_done=0;
    if (tid<NOBJ){
        const float* t=targets+(b*NOBJ+tid)*5;
        float x1=t[0],y1=t[1],x2=t[2],y2=t[3];
        s_tx1[tid]=x1;s_ty1[tid]=y1;s_tx2[tid]=x2;s_ty2[tid]=y2;
        s_ta[tid]=__fmul_rn(__fsub_rn(x2,x1),__fsub_rn(y2,y1));
        s_lab[tid]=t[4];
    }
    for (int i=tid;i<NW1*256;i+=BLK1) s_wh[i]=0;
    __syncthreads();

    const int d0=spl*PRB;
    const int cnt=(ND-d0<PRB)?(ND-d0):PRB;
    float px1[PPT],py1[PPT],px2[PPT],py2[PPT],pa[PPT];
    bool vld[PPT]; float bov[PPT]; int bj[PPT];
#pragma unroll
    for (int q=0;q<PPT;++q){
        int dl=tid*PPT+q; vld[q]=dl<cnt; bov[q]=-1.f; bj[q]=0;
        px1[q]=py1[q]=px2[q]=py2[q]=pa[q]=0.f;
        if (vld[q]){
            float4 p=reinterpret_cast<const float4*>(dbox)[d0+dl];
            float hw=__fmul_rn(0.5f,p.z), hh=__fmul_rn(0.5f,p.w);
            px1[q]=__fsub_rn(p.x,hw); py1[q]=__fsub_rn(p.y,hh);
            px2[q]=__fadd_rn(p.x,hw); py2[q]=__fadd_rn(p.y,hh);
            pa[q]=__fmul_rn(p.z,p.w);
        }
    }
    unsigned long long* kout=g_keys+(((size_t)b*NSPLIT+spl)*NW1+wv)*NOBJ;

    for (int c=0;c<NCHUNK;++c){
        float tx1c[CHUNK],ty1c[CHUNK],tx2c[CHUNK],ty2c[CHUNK],tac[CHUNK];
#pragma unroll
        for (int jj=0;jj<CHUNK;++jj){int j=c*CHUNK+jj;
            tx1c[jj]=s_tx1[j];ty1c[jj]=s_ty1[j];tx2c[jj]=s_tx2[j];ty2c[jj]=s_ty2[j];tac[jj]=s_ta[j];}
        float tb[CHUNK]; int td[CHUNK];
#pragma unroll
        for (int jj=0;jj<CHUNK;++jj){tb[jj]=-1.f;td[jj]=0;}
#pragma unroll
        for (int q=0;q<PPT;++q){
            if (!vld[q]) continue;
            const int d=d0+tid*PPT+q;
#pragma unroll
            for (int jj=0;jj<CHUNK;++jj){
                float iou=iou_rn(px1[q],py1[q],px2[q],py2[q],pa[q],
                                 tx1c[jj],ty1c[jj],tx2c[jj],ty2c[jj],tac[jj]);
                if (iou>bov[q]){bov[q]=iou;bj[q]=c*CHUNK+jj;}   // first-max (smallest j)
                if (iou>tb[jj]){tb[jj]=iou;td[jj]=d;}           // smallest d within lane
            }
        }
#pragma unroll
        for (int jj=0;jj<CHUNK;++jj){
            float m=tb[jj];
#pragma unroll
            for (int off=32;off>=1;off>>=1) m=fmaxf(m,__shfl_xor(m,off,64));
            unsigned long long msk=__ballot(tb[jj]==m);
            int lead=__builtin_ctzll(msk);                       // lowest lane = smallest d
            int dwin=__shfl(td[jj],lead,64);
            if (lane==0){
                unsigned long long enc=(m>=0.f)
                    ?(((unsigned long long)__float_as_uint(m)<<32)
                      |(unsigned long long)(0xFFFFFFFFu-(unsigned)dwin))
                    :0ull;                                       // fully-idle tail wave
                kout[c*CHUNK+jj]=enc;
            }
        }
    }

    // phase 2 (no-override view): CE, L1, signed ce_mined, histogram
    float* gce=(float*)g_ce4;
    float np=0.f,sl=0.f,sc=0.f;
#pragma unroll
    for (int q=0;q<PPT;++q){
        if (!vld[q]) continue;
        const int d=d0+tid*PPT+q;
        float2 cf=reinterpret_cast<const float2*>(conf_data)[(size_t)b*ND+d];
        float l=lse2(cf.x,cf.y);
        bool pos=!(bov[q]<0.5f);
        int jb=bj[q];
        int lab=pos?((int)s_lab[jb]+1):0;
        float cev=l-(lab>=1?cf.y:cf.x);
        float raw=pos?-cev:cev;                   // sign flags positive-masked entries
        gce[(size_t)b*ND+d]=raw;
        atomicAdd(&s_wh[wv*256+(int)(__float_as_uint(fmaxf(raw,0.f))>>24)],1);
        if (pos){
            np+=1.f; sc+=cev;
            float4 p=reinterpret_cast<const float4*>(dbox)[d];
            float4 ldv=reinterpret_cast<const float4*>(loc_data)[(size_t)b*ND+d];
            sl+=sl1_enc(p,s_tx1[jb],s_ty1[jb],s_tx2[jb],s_ty2[jb],ldv);
        }
    }
#pragma unroll
    for (int off=32;off>=1;off>>=1){
        np+=__shfl_xor(np,off,64); sl+=__shfl_xor(sl,off,64); sc+=__shfl_xor(sc,off,64);
    }
    if (lane==0){s_r1[wv]=np;s_r2[wv]=sl;s_r3[wv]=sc;}
    __syncthreads();
    if (tid==0){
        float a=0.f,bb2=0.f,cc=0.f;
        for (int w=0;w<NW1;++w){a+=s_r1[w];bb2+=s_r2[w];cc+=s_r3[w];}
        g_bp[(b*NSPLIT+spl)*3+0]=a;
        g_bp[(b*NSPLIT+spl)*3+1]=bb2;
        g_bp[(b*NSPLIT+spl)*3+2]=cc;
    }
    {
        int s=0;
        for (int w=0;w<NW1;++w) s+=s_wh[w*256+tid];
        g_hist[(size_t)(b*NSPLIT+spl)*256+tid]=s;
    }
}

// ---------------- K2: merge + corrections + radix select + fused finisher ----------------
__global__ __launch_bounds__(BLK2) void k2(const float* __restrict__ loc_data,
                                           const float* __restrict__ conf_data,
                                           const float* __restrict__ dbox,
                                           const float* __restrict__ targets,
                                           float* __restrict__ out){
    __shared__ float4 s_ce4[ND4];
    __shared__ unsigned long long s_km[NOBJ*16];
    __shared__ unsigned int s_dj[NOBJ];
    __shared__ float s_tx1[NOBJ],s_ty1[NOBJ],s_tx2[NOBJ],s_ty2[NOBJ],s_ta[NOBJ],s_lab[NOBJ];
    __shared__ int   s_hist[256];
    __shared__ int   s_wh[NW2*256];
    __shared__ float s_bpl[NSPLIT*3];
    __shared__ float s_rf[NW2]; __shared__ int s_ri[NW2];
    __shared__ int   s_wt[4];
    __shared__ float s_dnp,s_dsl,s_dsc;
    __shared__ int   s_sel,s_krem,s_kk,s_last;
    float* s_ce=(float*)s_ce4;

    const int b=blockIdx.x, tid=threadIdx.x, lane=tid&63, wv=tid>>6;

    if (tid<NOBJ){
        const float* t=targets+(b*NOBJ+tid)*5;
        float x1=t[0],y1=t[1],x2=t[2],y2=t[3];
        s_tx1[tid]=x1;s_ty1[tid]=y1;s_tx2[tid]=x2;s_ty2[tid]=y2;
        s_ta[tid]=__fmul_rn(__fsub_rn(x2,x1),__fsub_rn(y2,y1));
        s_lab[tid]=t[4];
    }
    if (tid<NOBJ*16){                    // parallel key merge: 3 loads/thread
        int j=tid>>4, s=tid&15;
        const unsigned long long* kp=g_keys+(size_t)b*NPART*NOBJ;
        unsigned long long m=kp[(size_t)s*NOBJ+j];
        unsigned long long o=kp[(size_t)(s+16)*NOBJ+j]; if(o>m)m=o;
        o=kp[(size_t)(s+32)*NOBJ+j]; if(o>m)m=o;
        s_km[tid]=m;
    }
    for (int i=tid;i<ND4;i+=BLK2) s_ce4[i]=g_ce4[(size_t)b*ND4+i];
    if (tid<256){
        int s=0;
        for (int sp=0;sp<NSPLIT;++sp) s+=g_hist[(size_t)(b*NSPLIT+sp)*256+tid];
        s_hist[tid]=s;
    }
    if (tid<NSPLIT*3) s_bpl[tid]=g_bp[b*NSPLIT*3+tid];
    __syncthreads();
    if (tid<NOBJ){
        unsigned long long m=s_km[tid*16];
        for (int s=1;s<16;++s){unsigned long long o=s_km[tid*16+s]; if(o>m)m=o;}
        s_dj[tid]=0xFFFFFFFFu-(unsigned)(m&0xFFFFFFFFull);
    }
    __syncthreads();

    // override corrections (<=50 priors forced positive, last-write-wins)
    float dnp=0.f,dsl=0.f,dsc=0.f;
    if (tid<NOBJ){
        unsigned d=s_dj[tid]; bool win=true;
        for (int j2=tid+1;j2<NOBJ;++j2) if (s_dj[j2]==d){win=false;break;}
        if (win){
            float4 p=reinterpret_cast<const float4*>(dbox)[d];
            float hw=__fmul_rn(0.5f,p.z), hh2=__fmul_rn(0.5f,p.w);
            float ppx1=__fsub_rn(p.x,hw),ppy1=__fsub_rn(p.y,hh2);
            float ppx2=__fadd_rn(p.x,hw),ppy2=__fadd_rn(p.y,hh2);
            float ppa=__fmul_rn(p.z,p.w);
            float bov=-1.f; int jb=0;
            for (int j=0;j<NOBJ;++j){     // bit-identical recompute of k1's match
                float iou=iou_rn(ppx1,ppy1,ppx2,ppy2,ppa,
                                 s_tx1[j],s_ty1[j],s_tx2[j],s_ty2[j],s_ta[j]);
                if (iou>bov){bov=iou;jb=j;}
            }
            bool oldpos=!(bov<0.5f);
            float2 cf=reinterpret_cast<const float2*>(conf_data)[(size_t)b*ND+d];
            float l=lse2(cf.x,cf.y);
            float4 ldv=reinterpret_cast<const float4*>(loc_data)[(size_t)b*ND+d];
            int labN=(int)s_lab[tid]+1;
            float ceN=l-(labN>=1?cf.y:cf.x);
            dsc+=ceN; dsl+=sl1_enc(p,s_tx1[tid],s_ty1[tid],s_tx2[tid],s_ty2[tid],ldv);
            if (oldpos){
                int labO=(int)s_lab[jb]+1;
                float ceO=l-(labO>=1?cf.y:cf.x);
                dsc-=ceO; dsl-=sl1_enc(p,s_tx1[jb],s_ty1[jb],s_tx2[jb],s_ty2[jb],ldv);
            } else dnp+=1.f;
            float oldraw=s_ce[d];
            atomicAdd(&s_hist[(int)(__float_as_uint(fmaxf(oldraw,0.f))>>24)],-1);
            atomicAdd(&s_hist[0],1);
            s_ce[d]=-ceN;
        }
    }
    if (wv==0){
#pragma unroll
        for (int off=32;off>=1;off>>=1){
            dnp+=__shfl_xor(dnp,off,64); dsl+=__shfl_xor(dsl,off,64); dsc+=__shfl_xor(dsc,off,64);
        }
        if (lane==0){s_dnp=dnp;s_dsl=dsl;s_dsc=dsc;}
    }
    __syncthreads();
    if (tid==0){
        float np=s_dnp, sl=s_dsl, sc=s_dsc;
        for (int i=0;i<NSPLIT;++i){np+=s_bpl[i*3];sl+=s_bpl[i*3+1];sc+=s_bpl[i*3+2];}
        int npi=(int)np; int k=npi*3; if(k<20)k=20; if(k>ND)k=ND;
        s_kk=k;
        g_part[b*5+0]=np; g_part[b*5+1]=sl; g_part[b*5+2]=sc; g_part[b*5+3]=(float)k;
    }
    __syncthreads();
    const int k=s_kk;

    // radix select: pass 1 free from histogram; passes 2-3 scan LDS
    unsigned prefix=0u,pmask=0u; int krem=k;
    for (int p=0;p<3;++p){
        const int shift=24-p*8;
        int cnt=0;
        if (p==0){
            if (tid<256) cnt=s_hist[tid];
        } else {
            for (int i=tid;i<NW2*256;i+=BLK2) s_wh[i]=0;
            __syncthreads();
            for (int it=0;it<ITER2;++it){
                int d=tid+it*BLK2;
                if (d<ND){
                    unsigned vb=__float_as_uint(fmaxf(s_ce[d],0.f));
                    if ((vb&pmask)==prefix)
                        atomicAdd(&s_wh[wv*256+(int)((vb>>shift)&255u)],1);
                }
            }
            __syncthreads();
            if (tid<256){
                for (int w=0;w<NW2;++w) cnt+=s_wh[w*256+tid];
            }
        }
        int S=cnt,add=0;
        if (tid<256){
#pragma unroll
            for (int off=1;off<64;off<<=1){
                int t=__shfl_down(S,off,64);
                if (lane+off<64) S+=t;
            }
            if (lane==0) s_wt[wv]=S;
        }
        __syncthreads();
        if (tid<256){
            for (int w=wv+1;w<4;++w) add+=s_wt[w];
            S+=add;
            int Snext=__shfl_down(S,1,64);
            if (lane==63) Snext=add;
            if (S>=krem && Snext<krem){s_sel=tid;s_krem=krem-(S-cnt);}
        }
        __syncthreads();
        prefix|=((unsigned)s_sel)<<shift;
        pmask|=255u<<shift;
        krem=s_krem;
        __syncthreads();
    }
    const float T=__uint_as_float(prefix);

    int cgt=0; float sgt=0.f;
    for (int it=0;it<ITER2;++it){
        int d=tid+it*BLK2;
        if (d<ND){
            float v=fmaxf(s_ce[d],0.f);
            if (v>T){cgt++;sgt+=v;}
        }
    }
#pragma unroll
    for (int off=32;off>=1;off>>=1){cgt+=__shfl_xor(cgt,off,64);sgt+=__shfl_xor(sgt,off,64);}
    if (lane==0){s_ri[wv]=cgt;s_rf[wv]=sgt;}
    __syncthreads();
    if (tid==0){
        int cg=0; float sg=0.f;
        for (int w=0;w<NW2;++w){cg+=s_ri[w];sg+=s_rf[w];}
        int need=k-cg;
        float stk=sg+(float)need*T;
        if (!(T>0.f)&&need>0){
            // T==0: stable index-order tie pool = {raw<=0}; original ce = |raw|
            int taken=0;
            for (int d=0;d<ND&&taken<need;++d){
                float r=s_ce[d];
                if (!(r>0.f)){stk+=fabsf(r);++taken;}
            }
        }
        g_part[b*5+4]=stk;
    }

    if (tid==0){__threadfence(); int old=atomicAdd(&g_done,1); s_last=(old==NB-1)?1:0;}
    __syncthreads();
    if (s_last&&tid<NB){
        __threadfence();
        volatile float* gp=g_part;
        float np=gp[tid*5+0],sl=gp[tid*5+1],sc=gp[tid*5+2],kk=gp[tid*5+3],st=gp[tid*5+4];
#pragma unroll
        for (int off=32;off>=1;off>>=1){
            np+=__shfl_xor(np,off,64);sl+=__shfl_xor(sl,off,64);
            sc+=__shfl_xor(sc,off,64);kk+=__shfl_xor(kk,off,64);st+=__shfl_xor(st,off,64);
        }
        if (tid==0){
            float loss_l=(np>0.f)?sl/(4.f*np):0.f;
            float lcp=(np>0.f)?sc/np:0.f;
            float lcn=(kk>0.f)?st/kk:0.f;
            out[0]=loss_l;out[1]=lcp+lcn;out[2]=lcp;out[3]=lcn;
        }
    }
}

extern "C" void kernel_launch(void* const* d_in, const int* in_sizes, int n_in,
                              void* d_out, int out_size, void* d_ws, size_t ws_size,
                              hipStream_t stream) {
    const float* loc     = (const float*)d_in[0];
    const float* conf    = (const float*)d_in[1];
    const float* dboxp   = (const float*)d_in[2];
    const float* targets = (const float*)d_in[3];
    float* out = (float*)d_out;

    k1<<<NB*NSPLIT, BLK1, 0, stream>>>(loc, conf, dboxp, targets);
    k2<<<NB, BLK2, 0, stream>>>(loc, conf, dboxp, targets, out);
}